// Round 11
// baseline (237.728 us; speedup 1.0000x reference)
//
#include <hip/hip_runtime.h>
#include <stdint.h>

#define NSEG 50
#define HID 128
#define KDIM 2144      // 64 + 2016 + 64
#define KD2 2176       // padded to 34*64 for BK=64
#define KD2B 4352      // row bytes fp16
#define NROW 20000     // 400 * 50
#define NROW_PAD 20096 // 157 * 128
#define GATES 512
#define NSEQ 400

typedef __attribute__((ext_vector_type(8))) _Float16 f16x8;
typedef __attribute__((ext_vector_type(4))) _Float16 f16x4;
typedef __attribute__((ext_vector_type(4))) float f32x4;
typedef __attribute__((ext_vector_type(4))) uint32_t u32x4;

#define GLB_SPACE __attribute__((address_space(1)))
#define LDS_SPACE __attribute__((address_space(3)))

__device__ __forceinline__ void g2lds16(const void* g, void* l) {
    __builtin_amdgcn_global_load_lds((const GLB_SPACE uint32_t*)g,
                                     (LDS_SPACE uint32_t*)l, 16, 0, 0);
}

// Levy pair-space tiling (i<j upper triangle of 64x64):
//  - 56 full 4x8 tiles (i-block a=i0/4, j-block b=j0/8, full iff j0>=i0+4): 1792 pairs
//  - 8 diag 4x4 tiles (even a, j0=i0+4): 128 pairs
//  - 16 triangles (within each i-block): 96 pairs
// k-layout (prep permutes W_ih columns to match, so GEMM is agnostic):
//  full:  k = 64   + 32*t + 8*q + w   (16B-aligned f16x8 stores)
//  diag:  k = 1856 + 16*d + 4*q + w   (8B-aligned f16x4 stores)
//  tri:   k = 1984 + 6*a  + e         (scalar)
__device__ const uint8_t TILES[56] = {
    0x01,0x02,0x03,0x04,0x05,0x06,0x07,        // a=0,  b=1..7
    0x09,0x0a,0x0b,0x0c,0x0d,0x0e,0x0f,        // a=1,  b=1..7
    0x12,0x13,0x14,0x15,0x16,0x17,             // a=2,  b=2..7
    0x1a,0x1b,0x1c,0x1d,0x1e,0x1f,             // a=3,  b=2..7
    0x23,0x24,0x25,0x26,0x27,                  // a=4,  b=3..7
    0x2b,0x2c,0x2d,0x2e,0x2f,                  // a=5,  b=3..7
    0x34,0x35,0x36,0x37,                       // a=6,  b=4..7
    0x3c,0x3d,0x3e,0x3f,                       // a=7,  b=4..7
    0x45,0x46,0x47,                            // a=8,  b=5..7
    0x4d,0x4e,0x4f,                            // a=9,  b=5..7
    0x56,0x57,                                 // a=10, b=6..7
    0x5e,0x5f,                                 // a=11, b=6..7
    0x67,                                      // a=12, b=7
    0x6f,                                      // a=13, b=7
};
__device__ const int8_t TRI_I[6] = {0,0,0,1,1,2};
__device__ const int8_t TRI_J[6] = {1,2,3,2,3,3};

// ---------------- features (blocks 0..799) + fused permuted weight-prep (800..863) ------
// dev_0 == 0, so S2 = (p1-p0)x(p2-p1) + (p2-p0)x(p3-p2); levy = 0.5(S2 - S2^T) upper tri.
// uv4T[c*25+v] transposed -> all tile-phase LDS reads are consecutive-v, conflict-free.
__global__ __launch_bounds__(512) void feat_kernel(const float* __restrict__ x,
                                                   const float* __restrict__ Wih,
                                                   const float* __restrict__ Whh,
                                                   const float* __restrict__ bih,
                                                   const float* __restrict__ bhh,
                                                   _Float16* __restrict__ feat,
                                                   _Float16* __restrict__ wh,
                                                   _Float16* __restrict__ whh16,
                                                   float* __restrict__ bias) {
    int bid = blockIdx.x;
    int tid = threadIdx.x;

    if (bid >= 800) {
        // ---- prep: permuted cast of W_ih (K-padded), cast W_hh, sum biases ----
        const int nwih = 512 * KD2;
        const int nwhh = 512 * HID;
        const int total = nwih + nwhh + 512;
        for (int idx = (bid - 800) * 512 + tid; idx < total; idx += 64 * 512) {
            if (idx < nwih) {
                int g = idx / KD2;
                int k = idx - g * KD2;
                float wv = 0.0f;
                if (k < KDIM) {
                    int kold;
                    if (k < 64 || k >= 2080) kold = k;          // lvl1 / start: identity
                    else {
                        int kl = k - 64;
                        int i, j;
                        if (kl < 1792) {
                            int t = kl >> 5, r = kl & 31;
                            int ab = TILES[t];
                            i = ((ab >> 3) << 2) + (r >> 3);
                            j = ((ab & 7) << 3) + (r & 7);
                        } else if (kl < 1920) {
                            int d = (kl - 1792) >> 4, r = (kl - 1792) & 15;
                            int a = d << 1;
                            i = (a << 2) + (r >> 2);
                            j = (a << 2) + 4 + (r & 3);
                        } else {
                            int qq = kl - 1920;
                            int a = qq / 6, e = qq - a * 6;
                            i = (a << 2) + TRI_I[e];
                            j = (a << 2) + TRI_J[e];
                        }
                        kold = 64 + 63 * i - (i * (i - 1)) / 2 + (j - i - 1);
                    }
                    wv = Wih[g * KDIM + kold];
                }
                wh[idx] = (_Float16)wv;
            } else if (idx < nwih + nwhh) {
                whh16[idx - nwih] = (_Float16)Whh[idx - nwih];
            } else {
                int g = idx - nwih - nwhh;
                bias[g] = bih[g] + bhh[g];
            }
        }
        return;
    }

    int b = bid / NSEG;
    int s = bid - b * NSEG;

    __shared__ __align__(16) float4 uv4T[1600];   // [c*25+v] = (u1,u2,v1,v2), 25.6 KB

    // setup (v-fast): coalesced x reads, uv4T build, lvl1/start stores, K-pad zeros
    for (int i = tid; i < 1600; i += 512) {
        int c = i / 25;
        int v = i - c * 25;
        const float* xp = x + (((size_t)b * 64 + c) * 200 + 4 * s) * 25 + v;
        float p0 = xp[0], p1 = xp[25], p2 = xp[50], p3 = xp[75];
        uv4T[i] = make_float4(p1 - p0, p2 - p0, p2 - p1, p3 - p2);
        size_t m = ((size_t)(b * 25 + v)) * NSEG + s;
        feat[m * KD2 + c] = (_Float16)(p3 - p0);             // lvl1
        feat[m * KD2 + 2080 + c] = (_Float16)p0;             // start
    }
    if (tid < 800) {
        int v = tid >> 5;
        int k = 2144 + (tid & 31);
        size_t m = ((size_t)(b * 25 + v)) * NSEG + s;
        feat[m * KD2 + k] = (_Float16)0.0f;
    }
    __syncthreads();

    // tile phase: half-wave hw (0..15) x lane v (0..24 active)
    int hw = tid >> 5;
    int v = tid & 31;
    bool act = v < 25;
    int vc = act ? v : 0;
    char* frow = (char*)feat + (((size_t)(b * 25 + vc)) * NSEG + s) * (size_t)(KD2 * 2);

    // full 4x8 tiles: 12 LDS reads amortize 32 pairs x 25 v; 16B-aligned stores
    for (int tt = hw; tt < 56; tt += 16) {
        int ab = TILES[tt];
        int i0 = (ab >> 3) << 2, j0 = (ab & 7) << 3;
        float4 ui[4], vj[8];
        for (int q = 0; q < 4; q++) ui[q] = uv4T[(i0 + q) * 25 + vc];
        for (int w = 0; w < 8; w++) vj[w] = uv4T[(j0 + w) * 25 + vc];
        for (int q = 0; q < 4; q++) {
            f16x8 out;
            for (int w = 0; w < 8; w++)
                out[w] = (_Float16)(0.5f * (ui[q].x * vj[w].z + ui[q].y * vj[w].w
                                          - vj[w].x * ui[q].z - vj[w].y * ui[q].w));
            if (act) *(f16x8*)(frow + 128 + (tt << 6) + (q << 4)) = out;
        }
    }
    // diag 4x4 tiles (8): half-waves 8..15
    if (hw >= 8) {
        int d = hw - 8, a = d << 1, i0 = a << 2, j0 = i0 + 4;
        float4 ui[4], vj[4];
        for (int q = 0; q < 4; q++) ui[q] = uv4T[(i0 + q) * 25 + vc];
        for (int w = 0; w < 4; w++) vj[w] = uv4T[(j0 + w) * 25 + vc];
        for (int q = 0; q < 4; q++) {
            f16x4 out;
            for (int w = 0; w < 4; w++)
                out[w] = (_Float16)(0.5f * (ui[q].x * vj[w].z + ui[q].y * vj[w].w
                                          - vj[w].x * ui[q].z - vj[w].y * ui[q].w));
            if (act) *(f16x4*)(frow + 3712 + (d << 5) + (q << 3)) = out;
        }
    }
    // triangles (16): half-wave hw = a, 6 scalar pairs
    {
        int i0 = hw << 2;
        for (int e = 0; e < 6; e++) {
            int i = i0 + TRI_I[e], j = i0 + TRI_J[e];
            float4 A = uv4T[i * 25 + vc], B = uv4T[j * 25 + vc];
            float val = 0.5f * (A.x * B.z + A.y * B.w - B.x * A.z - B.y * A.w);
            if (act) *(_Float16*)(frow + 3968 + hw * 12 + e * 2) = (_Float16)val;
        }
    }
}

// ---------------- GEMM: xproj2[s][q][gate] = feat @ W_ih^T + bias (fp16 out) ------------
// BM=128, BN=128, BK=64; grid 640, r6's bid&7 XCD-residue mapping (FETCH 52 MB measured).
// Cross-kt pipeline: single barrier/kt + double LDS buffer; ds_read all frags BEFORE
// issuing stage(kt+1) (no alias-wait), then 128 MFMAs overlap the in-flight staging —
// next barrier's vmcnt(0) drains loads issued ~620 cyc earlier.
__global__ __launch_bounds__(256, 2) void gemm_kernel(const _Float16* __restrict__ feat,
                                                      const _Float16* __restrict__ wh,
                                                      const float* __restrict__ bias,
                                                      _Float16* __restrict__ xproj2) {
    int bid = blockIdx.x;
    int x = bid & 7;
    int t = bid >> 3;
    int nb = t & 3;
    int mt = (t >> 2) * 8 + x;
    if (mt >= 157) return;
    int m0 = mt * 128;
    int n0 = nb * 128;
    int tid = threadIdx.x;
    int wave = tid >> 6;
    int lane = tid & 63;
    int quad = lane >> 4;
    int l15 = lane & 15;
    int wm = (wave & 1) * 64;
    int wn = (wave >> 1) * 64;

    int r8 = lane >> 3;                        // row within 8-row staging group
    int gcol = ((lane & 7) * 16) ^ (r8 * 16);  // XOR-swizzled source byte-col

    __shared__ __align__(16) _Float16 smem[32768];   // 64 KB: 2 x (16KB A | 16KB B)

    const f32x4 z4 = {0.f, 0.f, 0.f, 0.f};
    f32x4 acc[4][4];
    for (int i = 0; i < 4; i++)
        for (int j = 0; j < 4; j++) acc[i][j] = z4;

    const char* featB = (const char*)feat;
    const char* whB = (const char*)wh;

#define STAGE(kt, bsel) do {                                                         \
        size_t kb_ = (size_t)(kt) * 128;                                             \
        char* As_ = (char*)smem + (bsel) * 32768;                                    \
        char* Bs_ = As_ + 16384;                                                     \
        for (int it = 0; it < 4; it++) {                                             \
            int rb = it * 32 + wave * 8;                                             \
            g2lds16(featB + (size_t)(m0 + rb + r8) * KD2B + kb_ + gcol, As_ + rb * 128); \
            g2lds16(whB + (size_t)(n0 + rb + r8) * KD2B + kb_ + gcol, Bs_ + rb * 128);  \
        } } while (0)

    STAGE(0, 0);
    for (int kt = 0; kt < 34; kt++) {
        int cur = kt & 1;
        __syncthreads();    // drains vmcnt: stage(kt) complete; buf[cur^1] free to refill
        const char* As = (const char*)smem + cur * 32768;
        const char* Bs = As + 16384;
        f16x8 af[2][4], bf[2][4];
        for (int ks = 0; ks < 2; ks++) {
            int off = ((ks * 64) | (quad * 16)) ^ ((l15 & 7) * 16);
            for (int tt = 0; tt < 4; tt++) {
                af[ks][tt] = *(const f16x8*)(As + (wm + tt * 16 + l15) * 128 + off);
                bf[ks][tt] = *(const f16x8*)(Bs + (wn + tt * 16 + l15) * 128 + off);
            }
        }
        if (kt + 1 < 34) STAGE(kt + 1, cur ^ 1);   // async, overlaps the MFMA burst below
        for (int ks = 0; ks < 2; ks++)
            for (int mtl = 0; mtl < 4; mtl++)
                for (int ntl = 0; ntl < 4; ntl++)
                    acc[mtl][ntl] = __builtin_amdgcn_mfma_f32_16x16x32_f16(af[ks][mtl], bf[ks][ntl], acc[mtl][ntl], 0, 0, 0);
    }
#undef STAGE

    // epilogue: stage fp16 tile in LDS (row stride 132 halfwords), 256B-row dwordx4 stores
    __syncthreads();
    for (int ntl = 0; ntl < 4; ntl++) {
        int nl = wn + ntl * 16 + l15;
        float bv = bias[n0 + nl];
        for (int mtl = 0; mtl < 4; mtl++)
            for (int r = 0; r < 4; r++) {
                int ml = wm + mtl * 16 + quad * 4 + r;
                smem[ml * 132 + nl] = (_Float16)(acc[mtl][ntl][r] + bv);
            }
    }
    __syncthreads();
    {
        int row = tid >> 1;
        int seg = tid & 1;
        int m = m0 + row;
        if (m < NROW) {
            unsigned q = (unsigned)m / 50u;
            unsigned s = (unsigned)m - q * 50u;
            const char* src = (const char*)smem + row * 264 + seg * 128;
            char* dst = (char*)xproj2 + ((size_t)s * NSEQ + q) * 1024 + (size_t)n0 * 2 + seg * 128;
            for (int i = 0; i < 8; i++)
                *(u32x4*)(dst + i * 16) = *(const u32x4*)(src + i * 16);
        }
    }
}

// ---------------- LSTM: 100 blocks x 4 seqs x 8 waves; NO per-step global ops -----------
// 25 steps of xproj preloaded into LDS (104 KB), refilled once at midpoint; all h
// outputs buffered in LDS (51 KB), written out coalesced at the end.
__global__ __launch_bounds__(512, 2) void lstm_kernel(const _Float16* __restrict__ xproj2,
                                                      const _Float16* __restrict__ whh,
                                                      _Float16* __restrict__ hseq) {
    int bid = blockIdx.x;        // 0..99
    int tid = threadIdx.x;
    int wave = tid >> 6;         // 0..7
    int lane = tid & 63;
    int quad = lane >> 4;        // = this lane's seq
    int col = lane & 15;
    int hid = wave * 16 + col;   // this lane's hid

    __shared__ __align__(16) char xbuf[25 * 4 * 1040];       // 104,000 B, rows padded
    __shared__ __align__(16) _Float16 hst[NSEG * 4 * HID];   // 51,200 B, [s][seq][hid]
    __shared__ __align__(16) _Float16 hbuf[2][4 * 144];      // 2,304 B, stride 144

    // B-frags: bfrag[g][kq]; B[k][n] = whh[g*128 + hid][k]
    f16x8 bfrag[4][4];
    for (int g = 0; g < 4; g++) {
        int n = g * 128 + hid;
        for (int kq = 0; kq < 4; kq++)
            bfrag[g][kq] = *(const f16x8*)(whh + (size_t)n * HID + kq * 32 + quad * 8);
    }
    for (int i = tid; i < 2 * 4 * 144; i += 512) ((_Float16*)hbuf)[i] = (_Float16)0.0f;
    float cst = 0.0f;

    const char* xsrc = (const char*)xproj2;
    for (int r = wave; r < 100; r += 8)
        g2lds16(xsrc + ((size_t)((r >> 2) * NSEQ + bid * 4 + (r & 3))) * 1024 + lane * 16,
                xbuf + r * 1040);
    __syncthreads();

    const f32x4 z4 = {0.f, 0.f, 0.f, 0.f};
    for (int half = 0; half < 2; half++) {
        for (int ss = 0; ss < 25; ss++) {
            int s = half * 25 + ss;
            int cur = s & 1;
            int nxt = cur ^ 1;

            f16x8 afrag[4];
            for (int kq = 0; kq < 4; kq++)
                afrag[kq] = *(const f16x8*)(&hbuf[cur][(col & 3) * 144 + kq * 32 + quad * 8]);

            float xp[4];
            for (int g = 0; g < 4; g++)
                xp[g] = (float)(*(const _Float16*)(xbuf + (ss * 4 + quad) * 1040 +
                               (g * 128 + hid) * 2));

            f32x4 acc[4];
            for (int g = 0; g < 4; g++) {
                acc[g] = z4;
                for (int kq = 0; kq < 4; kq++)
                    acc[g] = __builtin_amdgcn_mfma_f32_16x16x32_f16(afrag[kq], bfrag[g][kq], acc[g], 0, 0, 0);
            }

            float gv[4];
            for (int g = 0; g < 4; g++) {
                float lo = (quad & 1) ? acc[g][1] : acc[g][0];
                float hi = (quad & 1) ? acc[g][3] : acc[g][2];
                gv[g] = (quad & 2) ? hi : lo;
            }

            float ip = gv[0] + xp[0];
            float fp = gv[1] + xp[1];
            float gp = gv[2] + xp[2];
            float op = gv[3] + xp[3];
            float si = __fdividef(1.0f, 1.0f + __expf(-ip));
            float sf = __fdividef(1.0f, 1.0f + __expf(-fp));
            float so = __fdividef(1.0f, 1.0f + __expf(-op));
            float eg = __expf(-2.0f * gp);
            float tg = __fdividef(1.0f - eg, 1.0f + eg);
            cst = sf * cst + si * tg;
            float ec = __expf(-2.0f * cst);
            float tc = __fdividef(1.0f - ec, 1.0f + ec);
            float hv = so * tc;
            _Float16 hv16 = (_Float16)hv;
            hbuf[nxt][quad * 144 + hid] = hv16;
            hst[(s * 4 + quad) * 128 + hid] = hv16;
            __syncthreads();
        }
        if (half == 0) {
            for (int r = wave; r < 100; r += 8)
                g2lds16(xsrc + ((size_t)((25 + (r >> 2)) * NSEQ + bid * 4 + (r & 3))) * 1024 + lane * 16,
                        xbuf + r * 1040);
            __syncthreads();
        }
    }

    const u32x4* src = (const u32x4*)hst;
    for (int i = tid; i < 3200; i += 512) {
        int s = i >> 6;
        int rem = i & 63;
        int seq = rem >> 4;
        int seg = rem & 15;
        u32x4 v = src[i];
        *(u32x4*)((char*)hseq + ((size_t)(s * NSEQ + bid * 4 + seq)) * 256 + seg * 16) = v;
    }
}

// ---------------- transpose: out[b][hid][s][v] = hseq[s][b*25+v][hid] -------------------
__global__ __launch_bounds__(256) void tr_kernel(const _Float16* __restrict__ hseq,
                                                 float* __restrict__ out) {
    int bid = blockIdx.x;        // 0..799 = b*50+s
    int b = bid / NSEG;
    int s = bid - b * NSEG;
    int tid = threadIdx.x;

    __shared__ _Float16 buf[25 * 130];   // [v][hid], padded 128->130

    const uint32_t* src32 = (const uint32_t*)(hseq + ((size_t)s * NSEQ + b * 25) * HID);
    uint32_t* buf32 = (uint32_t*)buf;
    for (int i = tid; i < 1600; i += 256) {
        int v = i >> 6;
        int d = i & 63;
        buf32[v * 65 + d] = src32[i];
    }
    __syncthreads();
    for (int i = tid; i < 3200; i += 256) {
        int hid = i / 25;
        int v = i - hid * 25;
        out[(((size_t)b * 128 + hid) * NSEG + s) * 25 + v] = (float)buf[v * 130 + hid];
    }
}

extern "C" void kernel_launch(void* const* d_in, const int* in_sizes, int n_in,
                              void* d_out, int out_size, void* d_ws, size_t ws_size,
                              hipStream_t stream) {
    const float* x = (const float*)d_in[0];
    const float* Wih = (const float*)d_in[1];
    const float* Whh = (const float*)d_in[2];
    const float* bih = (const float*)d_in[3];
    const float* bhh = (const float*)d_in[4];
    float* out = (float*)d_out;

    char* ws = (char*)d_ws;
    size_t off = 0;
    _Float16* feat = (_Float16*)(ws + off);   off += (size_t)NROW_PAD * KD2 * 2;      // 87.5 MB
    _Float16* xproj2 = (_Float16*)(ws + off); off += (size_t)NSEG * NSEQ * GATES * 2; // 20.5 MB
    _Float16* hseq = (_Float16*)(ws + off);   off += (size_t)NSEG * NSEQ * HID * 2;   // 5.1 MB
    _Float16* wh = (_Float16*)(ws + off);     off += (size_t)512 * KD2 * 2;           // 2.2 MB
    _Float16* whh16 = (_Float16*)(ws + off);  off += (size_t)512 * HID * 2;
    float* bias = (float*)(ws + off);         off += 512 * 4;

    hipLaunchKernelGGL(feat_kernel, dim3(864), dim3(512), 0, stream,
                       x, Wih, Whh, bih, bhh, feat, wh, whh16, bias);
    hipLaunchKernelGGL(gemm_kernel, dim3(640), dim3(256), 0, stream, feat, wh, bias, xproj2);
    hipLaunchKernelGGL(lstm_kernel, dim3(100), dim3(512), 0, stream, xproj2, whh16, hseq);
    hipLaunchKernelGGL(tr_kernel, dim3(16 * NSEG), dim3(256), 0, stream, hseq, out);
}